// Round 8
// baseline (112.648 us; speedup 1.0000x reference)
//
#include <hip/hip_runtime.h>
#include <math.h>

// Problem constants (reference file)
#define B_ 2
#define H_ 1080
#define W_ 1920
#define K_ 2048
#define P_ 256

// Borderless local SAT. tx0 = (ix-30) & ~3 (4-aligned -> 16B-aligned global
// float4 loads), ty0 = iy-30. Tile rows 0..60 (gy=ty0+ri), cols 0..63
// (gx=tx0+ci). After scans S[a][c] = sum of tile rows 0..a, cols 0..c.
// Sampling uses exclusive indices a0=jy-r-ty0-1 >= 0, c0=jx-r-tx0-1 >= 0
// (proof: jy >= iy-23, r <= 6, ty0 = iy-30 -> a0 >= 0; cols: tx0 >= ix-33
// -> c0 >= 0; a1 <= 59, c1 <= 62). Pad rows 61..63 zero so the col scan
// uses uniform 8-row segments. SS_=68 (mult of 4): b128/b64 LDS ops
// streaming-optimal on 32 banks.
#define SS_ 68                   // LDS row stride (floats)
#define SATN_ (64 * SS_)         // 4352 floats = 17408 B

// ---------------------------------------------------------------------------
// Per-keypoint precompute: FROZEN coordinate path (strict fp32 clamps/rint,
// double sin/cos rounded to fp32 — bit-identical to prior rounds).
// ---------------------------------------------------------------------------
__global__ __launch_bounds__(256) void kp_pre_kernel(
    const float* __restrict__ kp, const float* __restrict__ orient,
    float* __restrict__ ctl) {
  int bk = blockIdx.x * blockDim.x + threadIdx.x;
  if (bk >= B_ * K_) return;
  int b = bk >> 11;                       // K_ = 2048
  float kpy = kp[(size_t)bk * 2 + 0];
  float kpx = kp[(size_t)bk * 2 + 1];
  float validf = (kpy >= 0.0f) ? 1.0f : 0.0f;
  float y = fminf(fmaxf(kpy, 0.0f), (float)(H_ - 1));
  float x = fminf(fmaxf(kpx, 0.0f), (float)(W_ - 1));
  int iy = (int)rintf(y);
  int ix = (int)rintf(x);
  float theta = orient[((size_t)b * H_ + iy) * W_ + ix];
  double td = (double)theta;
  float st = (float)sin(td);
  float ct = (float)cos(td);
  int ty0 = iy - 30;
  int tx0 = (ix - 30) & ~3;               // 4-aligned (works for negatives)
  float4 c0v, c1v;
  c0v.x = y; c0v.y = x; c0v.z = st; c0v.w = ct;
  c1v.x = validf; c1v.y = __int_as_float(ty0);
  c1v.z = __int_as_float(tx0); c1v.w = 0.0f;
  float4* c4 = (float4*)(ctl + (size_t)bk * 8);
  c4[0] = c0v;
  c4[1] = c1v;
}

// ---------------------------------------------------------------------------
// Fused: register row-scan of the tile + LDS col-scan + sampling + norm.
// ---------------------------------------------------------------------------
__global__ __launch_bounds__(256) void bad_fused_kernel(
    const float* __restrict__ img, const float* __restrict__ ctl,
    const float* __restrict__ oy1, const float* __restrict__ ox1,
    const float* __restrict__ oy2, const float* __restrict__ ox2,
    const float* __restrict__ thr, const int* __restrict__ radii,
    float* __restrict__ out) {
  __shared__ float S[SATN_];
  __shared__ float wsum[4];

  int tid = threadIdx.x;
  int lane = tid & 63;
  int wv = tid >> 6;
  int bk = blockIdx.x;
  int b = bk >> 11;

  // ---- prefetch per-pair constants NOW: consumed only after the last
  // barrier; issuing here hides their latency under tile-load + scans.
  int p = tid;
  float a_y1 = oy1[p], a_x1 = ox1[p], a_y2 = oy2[p], a_x2 = ox2[p];
  float thv = thr[p];
  int r = radii[p];

  const float4* c4 = (const float4*)(ctl + (size_t)bk * 8);
  float4 ca = c4[0];
  float4 cb = c4[1];
  float y = ca.x, x = ca.y, st = ca.z, ct = ca.w;
  float validf = cb.x;
  int ty0 = __float_as_int(cb.y);
  int tx0 = __float_as_int(cb.z);
  const float* imgb = img + (size_t)b * H_ * W_;

  // zero pad rows 61..63 (never touched by row scan; read by col scan).
  if (tid < 3 * SS_) S[61 * SS_ + tid] = 0.0f;

  // ---- fused tile-load + row scan: thread 4i+s owns row i, cols 16s..16s+15
  if (tid < 244) {
    int i = tid >> 2, s = tid & 3;
    int gy = ty0 + i;
    int gx0 = tx0 + 16 * s;
    bool gyok = (gy >= 0) && (gy < H_);
    bool colfast = (tx0 >= 0) && (tx0 + 64 <= W_);   // block-uniform
    float v[16];
    if (gyok && colfast) {
      const float4* rp = (const float4*)(imgb + (size_t)gy * W_ + gx0);
      #pragma unroll
      for (int m = 0; m < 4; ++m) {
        float4 t = rp[m];
        v[4 * m + 0] = t.x; v[4 * m + 1] = t.y;
        v[4 * m + 2] = t.z; v[4 * m + 3] = t.w;
      }
    } else if (gyok) {
      #pragma unroll
      for (int k = 0; k < 16; ++k) {
        int gx = gx0 + k;
        v[k] = (gx >= 0 && gx < W_) ? imgb[(size_t)gy * W_ + gx] : 0.0f;
      }
    } else {
      #pragma unroll
      for (int k = 0; k < 16; ++k) v[k] = 0.0f;
    }
    #pragma unroll
    for (int k = 1; k < 16; ++k) v[k] += v[k - 1];   // in-register prefix
    // cross-segment offset: 4 segments are adjacent lanes (tid = 4i+s)
    float inc = v[15];
    float n1 = __shfl_up(inc, 1, 64); if (s >= 1) inc += n1;
    float n2 = __shfl_up(inc, 2, 64); if (s >= 2) inc += n2;
    float e = __shfl_up(inc, 1, 64);
    float off = (s >= 1) ? e : 0.0f;
    float* Rw = S + i * SS_ + 16 * s;                // 16B-aligned
    #pragma unroll
    for (int m = 0; m < 4; ++m) {
      float4 t;
      t.x = v[4 * m + 0] + off; t.y = v[4 * m + 1] + off;
      t.z = v[4 * m + 2] + off; t.w = v[4 * m + 3] + off;
      ((float4*)Rw)[m] = t;
    }
  }
  __syncthreads();

  // ---- col scan: ALL 256 threads. thread 8j+s owns cols 2j..2j+1, rows
  // 8s..8s+7 (b64). 8 segments of one column-pair are adjacent lanes ->
  // in-wave shuffle scan, no extra barrier. (R7 used 128 threads / 16-row
  // segments: 2 idle waves made the phase latency-exposed.)
  {
    int j = tid >> 3, s = tid & 7;
    float* Cb = S + (8 * s) * SS_ + 2 * j;
    float2 rv[8];
    #pragma unroll
    for (int k = 0; k < 8; ++k) rv[k] = *(float2*)(Cb + k * SS_);
    #pragma unroll
    for (int k = 1; k < 8; ++k) { rv[k].x += rv[k-1].x; rv[k].y += rv[k-1].y; }
    float sx = rv[7].x, sy = rv[7].y;
    float nx1 = __shfl_up(sx, 1, 64), ny1 = __shfl_up(sy, 1, 64);
    if (s >= 1) { sx += nx1; sy += ny1; }
    float nx2 = __shfl_up(sx, 2, 64), ny2 = __shfl_up(sy, 2, 64);
    if (s >= 2) { sx += nx2; sy += ny2; }
    float nx4 = __shfl_up(sx, 4, 64), ny4 = __shfl_up(sy, 4, 64);
    if (s >= 4) { sx += nx4; sy += ny4; }
    float ex = __shfl_up(sx, 1, 64), ey = __shfl_up(sy, 1, 64);
    float ofx = (s >= 1) ? ex : 0.0f, ofy = (s >= 1) ? ey : 0.0f;
    #pragma unroll
    for (int k = 0; k < 8; ++k) {
      float2 t; t.x = rv[k].x + ofx; t.y = rv[k].y + ofy;
      *(float2*)(Cb + k * SS_) = t;
    }
  }
  __syncthreads();

  // ---- per-pair sampling (FROZEN coordinate path) ----
  float rdy1 = __fadd_rn(__fmul_rn(a_x1, st), __fmul_rn(a_y1, ct));
  float rdx1 = __fsub_rn(__fmul_rn(a_x1, ct), __fmul_rn(a_y1, st));
  float rdy2 = __fadd_rn(__fmul_rn(a_x2, st), __fmul_rn(a_y2, ct));
  float rdx2 = __fsub_rn(__fmul_rn(a_x2, ct), __fmul_rn(a_y2, st));
  float p1y = __fadd_rn(y, rdy1);
  float p1x = __fadd_rn(x, rdx1);
  float p2y = __fadd_rn(y, rdy2);
  float p2x = __fadd_rn(x, rdx2);

  float tt = 2.0f * (float)r + 1.0f;
  float w = __fdiv_rn(1.0f, __fmul_rn(tt, tt));   // fp32(1/(2r+1)^2)

  // sample 1 — indices provably in [0,63]; int clamps kept as OOB hard stop.
  int jy = (int)fminf(fmaxf(rintf(p1y), 0.0f), (float)(H_ - 1));
  int jx = (int)fminf(fmaxf(rintf(p1x), 0.0f), (float)(W_ - 1));
  int a0 = min(max(jy - r - ty0 - 1, 0), 63);
  int a1 = min(max(jy + r - ty0, 0), 63);
  int c0 = min(max(jx - r - tx0 - 1, 0), 63);
  int c1 = min(max(jx + r - tx0, 0), 63);
  float s1 = ((S[a1 * SS_ + c1] - S[a0 * SS_ + c1])
              - S[a1 * SS_ + c0]) + S[a0 * SS_ + c0];
  float v1 = __fmul_rn(s1, w);
  // sample 2
  jy = (int)fminf(fmaxf(rintf(p2y), 0.0f), (float)(H_ - 1));
  jx = (int)fminf(fmaxf(rintf(p2x), 0.0f), (float)(W_ - 1));
  a0 = min(max(jy - r - ty0 - 1, 0), 63);
  a1 = min(max(jy + r - ty0, 0), 63);
  c0 = min(max(jx - r - tx0 - 1, 0), 63);
  c1 = min(max(jx + r - tx0, 0), 63);
  float s2 = ((S[a1 * SS_ + c1] - S[a0 * SS_ + c1])
              - S[a1 * SS_ + c0]) + S[a0 * SS_ + c0];
  float v2 = __fmul_rn(s2, w);

  float d = __fsub_rn(__fsub_rn(v1, v2), thv);

  // block L2-norm over P=256
  float sq = __fmul_rn(d, d);
  #pragma unroll
  for (int off = 32; off >= 1; off >>= 1) sq += __shfl_xor(sq, off, 64);
  if (lane == 0) wsum[wv] = sq;
  __syncthreads();
  float total = wsum[0] + wsum[1] + wsum[2] + wsum[3];
  float norm = sqrtf(total);
  float q = __fdiv_rn(d, fmaxf(norm, 1e-12f));
  out[(size_t)bk * P_ + p] = __fmul_rn(q, validf);
}

// ---------------------------------------------------------------------------

extern "C" void kernel_launch(void* const* d_in, const int* in_sizes, int n_in,
                              void* d_out, int out_size, void* d_ws, size_t ws_size,
                              hipStream_t stream) {
  const float* image    = (const float*)d_in[0];
  const float* kp       = (const float*)d_in[1];
  const float* orient   = (const float*)d_in[2];
  const float* oy1      = (const float*)d_in[3];
  const float* ox1      = (const float*)d_in[4];
  const float* oy2      = (const float*)d_in[5];
  const float* ox2      = (const float*)d_in[6];
  const float* thr      = (const float*)d_in[7];
  const int*   radii    = (const int*)d_in[8];
  float* out = (float*)d_out;
  float* ctl = (float*)d_ws;              // 4096 * 8 floats = 128 KB

  kp_pre_kernel<<<(B_ * K_ + 255) / 256, 256, 0, stream>>>(kp, orient, ctl);
  bad_fused_kernel<<<B_ * K_, 256, 0, stream>>>(
      image, ctl, oy1, ox1, oy2, ox2, thr, radii, out);
}

// Round 9
// 104.262 us; speedup vs baseline: 1.0804x; 1.0804x over previous
//
#include <hip/hip_runtime.h>
#include <math.h>

// Problem constants (reference file)
#define B_ 2
#define H_ 1080
#define W_ 1920
#define K_ 2048
#define P_ 256

// Borderless local SAT. tx0 = (ix-30) & ~3 (4-aligned -> 16B-aligned global
// float4 loads), ty0 = iy-30. Tile rows 0..60, cols 0..63. After scans
// S[a][c] = sum of tile rows 0..a, cols 0..c. Sampling uses exclusive
// indices a0=jy-r-ty0-1 >= 0, c0=jx-r-tx0-1 >= 0 (jy >= iy-23, r <= 6,
// ty0 = iy-30 -> a0 >= 0; tx0 >= ix-33 -> c0 >= 0; a1 <= 59, c1 <= 62).
// Pad rows 61..63 zero so the col scan uses uniform 8-row segments.
//
// LAYOUT: row a lives at a*SS_ + (a>>3)*8 — an 8-float pad per 8-row group.
// Group stride = 8*68+8 = 552 ≡ 8 (mod 32 banks), so the col scan's 8
// segments x 8 column-pairs per wave spread exactly 4 words/bank = the b64
// bandwidth floor (R8's unpadded version piled 8/bank -> 2x phase cost).
// Row starts stay 16B-aligned (68, 8, 16s all mult of 4) for b128 stores.
#define SS_ 68                    // floats per row (before group pad)
#define ROWOFF(a) ((a) * SS_ + ((a) >> 3) * 8)
#define SATN_ (64 * SS_ + 56)     // 4408 floats

// ---------------------------------------------------------------------------
// Per-keypoint precompute: FROZEN coordinate path (strict fp32 clamps/rint,
// double sin/cos rounded to fp32 — bit-identical to prior rounds).
// ---------------------------------------------------------------------------
__global__ __launch_bounds__(256) void kp_pre_kernel(
    const float* __restrict__ kp, const float* __restrict__ orient,
    float* __restrict__ ctl) {
  int bk = blockIdx.x * blockDim.x + threadIdx.x;
  if (bk >= B_ * K_) return;
  int b = bk >> 11;                       // K_ = 2048
  float kpy = kp[(size_t)bk * 2 + 0];
  float kpx = kp[(size_t)bk * 2 + 1];
  float validf = (kpy >= 0.0f) ? 1.0f : 0.0f;
  float y = fminf(fmaxf(kpy, 0.0f), (float)(H_ - 1));
  float x = fminf(fmaxf(kpx, 0.0f), (float)(W_ - 1));
  int iy = (int)rintf(y);
  int ix = (int)rintf(x);
  float theta = orient[((size_t)b * H_ + iy) * W_ + ix];
  double td = (double)theta;
  float st = (float)sin(td);
  float ct = (float)cos(td);
  int ty0 = iy - 30;
  int tx0 = (ix - 30) & ~3;               // 4-aligned (works for negatives)
  float4 c0v, c1v;
  c0v.x = y; c0v.y = x; c0v.z = st; c0v.w = ct;
  c1v.x = validf; c1v.y = __int_as_float(ty0);
  c1v.z = __int_as_float(tx0); c1v.w = 0.0f;
  float4* c4 = (float4*)(ctl + (size_t)bk * 8);
  c4[0] = c0v;
  c4[1] = c1v;
}

// ---------------------------------------------------------------------------
// Fused: register row-scan of the tile + LDS col-scan + sampling + norm.
// ---------------------------------------------------------------------------
__global__ __launch_bounds__(256) void bad_fused_kernel(
    const float* __restrict__ img, const float* __restrict__ ctl,
    const float* __restrict__ oy1, const float* __restrict__ ox1,
    const float* __restrict__ oy2, const float* __restrict__ ox2,
    const float* __restrict__ thr, const int* __restrict__ radii,
    float* __restrict__ out) {
  __shared__ float S[SATN_];
  __shared__ float wsum[4];

  int tid = threadIdx.x;
  int lane = tid & 63;
  int wv = tid >> 6;
  int bk = blockIdx.x;
  int b = bk >> 11;

  const float4* c4 = (const float4*)(ctl + (size_t)bk * 8);
  float4 ca = c4[0];
  float4 cb = c4[1];
  float y = ca.x, x = ca.y, st = ca.z, ct = ca.w;
  float validf = cb.x;
  int ty0 = __float_as_int(cb.y);
  int tx0 = __float_as_int(cb.z);
  const float* imgb = img + (size_t)b * H_ * W_;

  // zero pad rows 61..63 (contiguous 204 floats at ROWOFF(61); never
  // touched by row scan, read by col scan). Every read cell written every
  // launch: no residue dependence.
  if (tid < 204) S[ROWOFF(61) + tid] = 0.0f;

  // ---- fused tile-load + row scan: thread 4i+s owns row i, cols 16s..16s+15
  if (tid < 244) {
    int i = tid >> 2, s = tid & 3;
    int gy = ty0 + i;
    int gx0 = tx0 + 16 * s;
    bool gyok = (gy >= 0) && (gy < H_);
    bool colfast = (tx0 >= 0) && (tx0 + 64 <= W_);   // block-uniform
    float v[16];
    if (gyok && colfast) {
      const float4* rp = (const float4*)(imgb + (size_t)gy * W_ + gx0);
      #pragma unroll
      for (int m = 0; m < 4; ++m) {
        float4 t = rp[m];
        v[4 * m + 0] = t.x; v[4 * m + 1] = t.y;
        v[4 * m + 2] = t.z; v[4 * m + 3] = t.w;
      }
    } else if (gyok) {
      #pragma unroll
      for (int k = 0; k < 16; ++k) {
        int gx = gx0 + k;
        v[k] = (gx >= 0 && gx < W_) ? imgb[(size_t)gy * W_ + gx] : 0.0f;
      }
    } else {
      #pragma unroll
      for (int k = 0; k < 16; ++k) v[k] = 0.0f;
    }
    #pragma unroll
    for (int k = 1; k < 16; ++k) v[k] += v[k - 1];   // in-register prefix
    // cross-segment offset: 4 segments are adjacent lanes (tid = 4i+s)
    float inc = v[15];
    float n1 = __shfl_up(inc, 1, 64); if (s >= 1) inc += n1;
    float n2 = __shfl_up(inc, 2, 64); if (s >= 2) inc += n2;
    float e = __shfl_up(inc, 1, 64);
    float off = (s >= 1) ? e : 0.0f;
    float* Rw = S + ROWOFF(i) + 16 * s;              // 16B-aligned
    #pragma unroll
    for (int m = 0; m < 4; ++m) {
      float4 t;
      t.x = v[4 * m + 0] + off; t.y = v[4 * m + 1] + off;
      t.z = v[4 * m + 2] + off; t.w = v[4 * m + 3] + off;
      ((float4*)Rw)[m] = t;
    }
  }
  __syncthreads();

  // ---- col scan: ALL 256 threads. thread 8j+s owns cols 2j..2j+1, rows
  // 8s..8s+7 (b64). Segments of a column-pair are adjacent lanes -> in-wave
  // shuffle scan. Group pad makes segment stride 552 ≡ 8 mod 32: 4
  // words/bank = floor (the R8 regression was 8/bank at stride 544 ≡ 0).
  {
    int j = tid >> 3, s = tid & 7;
    float* Cb = S + 552 * s + 2 * j;      // ROWOFF(8s) + 2j
    float2 rv[8];
    #pragma unroll
    for (int k = 0; k < 8; ++k) rv[k] = *(float2*)(Cb + k * SS_);
    #pragma unroll
    for (int k = 1; k < 8; ++k) { rv[k].x += rv[k-1].x; rv[k].y += rv[k-1].y; }
    float sx = rv[7].x, sy = rv[7].y;
    float nx1 = __shfl_up(sx, 1, 64), ny1 = __shfl_up(sy, 1, 64);
    if (s >= 1) { sx += nx1; sy += ny1; }
    float nx2 = __shfl_up(sx, 2, 64), ny2 = __shfl_up(sy, 2, 64);
    if (s >= 2) { sx += nx2; sy += ny2; }
    float nx4 = __shfl_up(sx, 4, 64), ny4 = __shfl_up(sy, 4, 64);
    if (s >= 4) { sx += nx4; sy += ny4; }
    float ex = __shfl_up(sx, 1, 64), ey = __shfl_up(sy, 1, 64);
    float ofx = (s >= 1) ? ex : 0.0f, ofy = (s >= 1) ? ey : 0.0f;
    #pragma unroll
    for (int k = 0; k < 8; ++k) {
      float2 t; t.x = rv[k].x + ofx; t.y = rv[k].y + ofy;
      *(float2*)(Cb + k * SS_) = t;
    }
  }
  __syncthreads();

  // ---- per-pair sampling (FROZEN coordinate path; loads post-barrier as
  // in R7 — R8's entry-prefetch was confounded with the regression) ----
  int p = tid;
  float a_y1 = oy1[p], a_x1 = ox1[p], a_y2 = oy2[p], a_x2 = ox2[p];
  float rdy1 = __fadd_rn(__fmul_rn(a_x1, st), __fmul_rn(a_y1, ct));
  float rdx1 = __fsub_rn(__fmul_rn(a_x1, ct), __fmul_rn(a_y1, st));
  float rdy2 = __fadd_rn(__fmul_rn(a_x2, st), __fmul_rn(a_y2, ct));
  float rdx2 = __fsub_rn(__fmul_rn(a_x2, ct), __fmul_rn(a_y2, st));
  float p1y = __fadd_rn(y, rdy1);
  float p1x = __fadd_rn(x, rdx1);
  float p2y = __fadd_rn(y, rdy2);
  float p2x = __fadd_rn(x, rdx2);

  int r = radii[p];
  float tt = 2.0f * (float)r + 1.0f;
  float w = __fdiv_rn(1.0f, __fmul_rn(tt, tt));   // fp32(1/(2r+1)^2)

  // sample 1 — indices provably in [0,63]; clamps kept as OOB hard stop.
  int jy = (int)fminf(fmaxf(rintf(p1y), 0.0f), (float)(H_ - 1));
  int jx = (int)fminf(fmaxf(rintf(p1x), 0.0f), (float)(W_ - 1));
  int a0 = min(max(jy - r - ty0 - 1, 0), 63);
  int a1 = min(max(jy + r - ty0, 0), 63);
  int c0 = min(max(jx - r - tx0 - 1, 0), 63);
  int c1 = min(max(jx + r - tx0, 0), 63);
  int ro0 = ROWOFF(a0), ro1 = ROWOFF(a1);
  float s1 = ((S[ro1 + c1] - S[ro0 + c1]) - S[ro1 + c0]) + S[ro0 + c0];
  float v1 = __fmul_rn(s1, w);
  // sample 2
  jy = (int)fminf(fmaxf(rintf(p2y), 0.0f), (float)(H_ - 1));
  jx = (int)fminf(fmaxf(rintf(p2x), 0.0f), (float)(W_ - 1));
  a0 = min(max(jy - r - ty0 - 1, 0), 63);
  a1 = min(max(jy + r - ty0, 0), 63);
  c0 = min(max(jx - r - tx0 - 1, 0), 63);
  c1 = min(max(jx + r - tx0, 0), 63);
  ro0 = ROWOFF(a0); ro1 = ROWOFF(a1);
  float s2 = ((S[ro1 + c1] - S[ro0 + c1]) - S[ro1 + c0]) + S[ro0 + c0];
  float v2 = __fmul_rn(s2, w);

  float d = __fsub_rn(__fsub_rn(v1, v2), thr[p]);

  // block L2-norm over P=256
  float sq = __fmul_rn(d, d);
  #pragma unroll
  for (int off = 32; off >= 1; off >>= 1) sq += __shfl_xor(sq, off, 64);
  if (lane == 0) wsum[wv] = sq;
  __syncthreads();
  float total = wsum[0] + wsum[1] + wsum[2] + wsum[3];
  float norm = sqrtf(total);
  float q = __fdiv_rn(d, fmaxf(norm, 1e-12f));
  out[(size_t)bk * P_ + p] = __fmul_rn(q, validf);
}

// ---------------------------------------------------------------------------

extern "C" void kernel_launch(void* const* d_in, const int* in_sizes, int n_in,
                              void* d_out, int out_size, void* d_ws, size_t ws_size,
                              hipStream_t stream) {
  const float* image    = (const float*)d_in[0];
  const float* kp       = (const float*)d_in[1];
  const float* orient   = (const float*)d_in[2];
  const float* oy1      = (const float*)d_in[3];
  const float* ox1      = (const float*)d_in[4];
  const float* oy2      = (const float*)d_in[5];
  const float* ox2      = (const float*)d_in[6];
  const float* thr      = (const float*)d_in[7];
  const int*   radii    = (const int*)d_in[8];
  float* out = (float*)d_out;
  float* ctl = (float*)d_ws;              // 4096 * 8 floats = 128 KB

  kp_pre_kernel<<<(B_ * K_ + 255) / 256, 256, 0, stream>>>(kp, orient, ctl);
  bad_fused_kernel<<<B_ * K_, 256, 0, stream>>>(
      image, ctl, oy1, ox1, oy2, ox2, thr, radii, out);
}